// Round 14
// baseline (409.279 us; speedup 1.0000x reference)
//
#include <hip/hip_runtime.h>
#include <hip/hip_fp16.h>

#define B_ 64
#define L_ 128
#define E_ 300
#define HD_ 200
#define H_ 400
#define S_ 50
#define START_ 48
#define END_ 49
#define NG_ 1600
#define BL_ 8192

// ---- ws layout (bytes) ----
#define OFF_XG   0ull                          // bf16 [8192][1600]  26,214,400
#define OFF_LSTM 26214400ull                   // f32  [8192][400]   13,107,200
#define OFF_ABF  OFF_LSTM                      // bf16 [8192][320]    5,242,880 (overlay)
#define OFF_BBF  (OFF_LSTM + 5242880ull)       // bf16 [1664][320]    1,064,960 (overlay)
#define OFF_SH   (OFF_LSTM + 13107200ull)      // max(w8 320,000 ; feats 1,638,400)
#define OFF_INV  (OFF_SH + 1638400ull)         // f32 [1600]  6,400
#define OFF_WTT  (OFF_INV + 6400ull)           // f32 [400][50] 80,000
#define OFF_BIA  (OFF_WTT + 80000ull)          // f32 [1600]  6,400
#define OFF_PART (OFF_BIA + 6400ull)           // f32 [64] per-batch partials

#define NA_T 2621440   // 8192*320
#define NB_T 532480    // 1664*320
// prep items = NA_T + NB_T + 20000 (wtagT) + 1600 (biasC) = 3,175,520
// grid 12405*256 = 3,175,680 >= 3,175,520
#define PREP_BLOCKS 12405

typedef __attribute__((ext_vector_type(8))) short short8;
typedef __attribute__((ext_vector_type(4))) float f32x4;

__device__ __forceinline__ unsigned short f32_to_bf16(float f) {
    unsigned u = __float_as_uint(f);
    unsigned r = u + 0x7fffu + ((u >> 16) & 1u);
    return (unsigned short)(r >> 16);
}
__device__ __forceinline__ float bf16_to_f32(unsigned short s) {
    return __uint_as_float(((unsigned)s) << 16);
}
// 4-wide int8 dot with i32 accumulate: v_dot4_i32_i8 (fallback: manual sext).
__device__ __forceinline__ int dot4(unsigned a, unsigned b, int c) {
#if __has_builtin(__builtin_amdgcn_sdot4)
    return __builtin_amdgcn_sdot4(a, b, c, false);
#else
    c += (int)(signed char)(a)       * (int)(signed char)(b);
    c += (int)(signed char)(a >> 8)  * (int)(signed char)(b >> 8);
    c += (int)(signed char)(a >> 16) * (int)(signed char)(b >> 16);
    c += (int)(signed char)(a >> 24) * (int)(signed char)(b >> 24);
    return c;
#endif
}
// wave-uniform lane read (SGPR result, VALU-cheap; fallback shfl)
__device__ __forceinline__ unsigned rlane(unsigned v, int l) {
#if __has_builtin(__builtin_amdgcn_readlane)
    return __builtin_amdgcn_readlane(v, l);
#else
    return (unsigned)__shfl((int)v, l, 64);
#endif
}

// ---------------- prep: A' gather->bf16(padded 320), B' weights->bf16, wtagT, biasC.
__global__ void prep_kernel(const int* __restrict__ words, const float* __restrict__ emb,
                            const float* __restrict__ wihf, const float* __restrict__ wihb,
                            const float* __restrict__ bfc, const float* __restrict__ bbc,
                            const float* __restrict__ wtag,
                            unsigned short* __restrict__ Abf, unsigned short* __restrict__ Bbf,
                            float* __restrict__ wtagT, float* __restrict__ biasC) {
    long g = (long)blockIdx.x * 256 + threadIdx.x;
    if (g < NA_T) {
        int i = (int)(g / 320), k = (int)(g % 320);
        float v = (k < E_) ? emb[(long)words[i] * E_ + k] : 0.f;
        Abf[g] = f32_to_bf16(v);
        return;
    }
    g -= NA_T;
    if (g < NB_T) {
        int r = (int)(g / 320), k = (int)(g % 320);
        float v = 0.f;
        if (r < NG_ && k < E_) v = (r < 800) ? wihf[r * E_ + k] : wihb[(r - 800) * E_ + k];
        Bbf[g] = f32_to_bf16(v);
        return;
    }
    g -= NB_T;
    if (g < 20000) {
        int k = (int)(g / S_), s = (int)(g % S_);
        wtagT[g] = wtag[s * H_ + k];
        return;
    }
    g -= 20000;
    if (g < 1600) { biasC[g] = (g < 800) ? bfc[g] : bbc[g - 800]; return; }
}

// ---------------- w_hh quant: one WAVE per row. Global w8 layout (k-major chunks):
//   [dir] { chunks [j=0..11][row 0..799] uint4 (k=16j..16j+15) at (j*800+row)*16,
//           tails  [row] uint2 (k=192..199) at 153600 + row*8 }   (160,000 B per dir)
__global__ __launch_bounds__(256) void quant_kernel(const float* __restrict__ whh_f,
                                                    const float* __restrict__ whh_b,
                                                    signed char* __restrict__ w8,
                                                    float* __restrict__ invs) {
    int gw = (int)((blockIdx.x * 256 + threadIdx.x) >> 6);
    int lane = threadIdx.x & 63;
    if (gw >= 1600) return;
    int dir = gw / 800, row = gw % 800;
    const float* w = (dir ? whh_b : whh_f) + row * HD_;
    float m = 1e-20f;
    for (int k = lane; k < HD_; k += 64) m = fmaxf(m, fabsf(w[k]));
    for (int off = 32; off; off >>= 1) m = fmaxf(m, __shfl_xor(m, off));
    float s = 127.f / m;
    if (lane < 50) {
        int k0 = lane * 4;
        unsigned pk = 0;
#pragma unroll
        for (int i = 0; i < 4; ++i) {
            int v = (int)rintf(w[k0 + i] * s);
            pk |= ((unsigned)(v & 0xff)) << (8 * i);
        }
        unsigned char* base = (unsigned char*)w8 + dir * 160000;
        if (lane < 48) {
            int j = lane >> 2, wsel = lane & 3;
            *(unsigned*)(base + (size_t)(j * 800 + row) * 16 + wsel * 4) = pk;
        } else {
            *(unsigned*)(base + 153600 + (size_t)row * 8 + (lane - 48) * 4) = pk;
        }
    }
    if (lane == 0) invs[gw] = m / 16129.f;   // m/(127*127)
}

// ---------------- xg GEMM (MFMA bf16), staged from pre-converted bf16 A'/B'. (unchanged)
__global__ __launch_bounds__(256) void xg_gemm(const unsigned short* __restrict__ Abf,
                                               const unsigned short* __restrict__ Bbf,
                                               const float* __restrict__ biasC,
                                               unsigned short* __restrict__ xg) {
    __shared__ unsigned short As[128 * 40];
    __shared__ unsigned short Bs[128 * 40];
    int tid = threadIdx.x;
    int bm = blockIdx.y * 128;
    int bn = blockIdx.x * 128;
    int srow = tid >> 1, half = tid & 1;
    int lane = tid & 63, wave = tid >> 6, r16 = lane & 15, kh = lane >> 4;

    f32x4 acc[2][8];
#pragma unroll
    for (int mi = 0; mi < 2; ++mi)
#pragma unroll
        for (int ni = 0; ni < 8; ++ni) acc[mi][ni] = (f32x4){0.f, 0.f, 0.f, 0.f};

    const unsigned short* Ar = Abf + (long)(bm + srow) * 320;
    const unsigned short* Br = Bbf + (long)(bn + srow) * 320;

    for (int k0 = 0; k0 < 320; k0 += 32) {
#pragma unroll
        for (int j = 0; j < 2; ++j) {
            int off = half * 16 + j * 8;
            *(uint4*)&As[srow * 40 + off] = *(const uint4*)(Ar + k0 + off);
            *(uint4*)&Bs[srow * 40 + off] = *(const uint4*)(Br + k0 + off);
        }
        __syncthreads();
        short8 af[2], bfv[8];
#pragma unroll
        for (int mi = 0; mi < 2; ++mi)
            af[mi] = *(const short8*)&As[(wave * 32 + mi * 16 + r16) * 40 + kh * 8];
#pragma unroll
        for (int ni = 0; ni < 8; ++ni)
            bfv[ni] = *(const short8*)&Bs[(ni * 16 + r16) * 40 + kh * 8];
#pragma unroll
        for (int mi = 0; mi < 2; ++mi)
#pragma unroll
            for (int ni = 0; ni < 8; ++ni)
                acc[mi][ni] = __builtin_amdgcn_mfma_f32_16x16x32_bf16(af[mi], bfv[ni], acc[mi][ni], 0, 0, 0);
        __syncthreads();
    }
#pragma unroll
    for (int ni = 0; ni < 8; ++ni) {
        int g = bn + ni * 16 + r16;
        if (g < NG_) {
            float bias = biasC[g];
#pragma unroll
            for (int mi = 0; mi < 2; ++mi) {
#pragma unroll
                for (int r = 0; r < 4; ++r) {
                    int row = bm + wave * 32 + mi * 16 + kh * 4 + r;
                    xg[(long)row * NG_ + g] = f32_to_bf16(acc[mi][ni][r] + bias);
                }
            }
        }
    }
}

// ---------------- LSTM recurrence, two-pipe balanced (R12 all-LDS=3300cyc/step LDS-bound;
// R13 all-VMEM-spill=2440 L2-bound; the pipes are independent):
//  - chunks j=0..7 (128B/row, 102.4KB) LDS-resident  -> 8 b128 reads/thread/step
//  - chunks j=8..11 + tail (72B/row = 18 VGPR) in registers -> CANNOT meaningfully spill
//    (every prior spill was demand>cap: 100-235 wanted vs 60-128 given; 18 fits any cap)
//  - h via ONE ds_read_b128/wave + 52 v_readlane (SGPR) -> kills 169 broadcast LDS ops/step
// 832 thr (800 active, 1 gate-row each), q=tid/200: 0=i 1=f 2=g 3=o.
__global__ __launch_bounds__(832) void lstm_rec(const unsigned short* __restrict__ xg,
                                                const signed char* __restrict__ w8,
                                                const float* __restrict__ invs,
                                                float* __restrict__ lstm_out) {
    __shared__ __align__(16) uint4 wlds[6400];          // chunks j=0..7: [j][row] 102,400 B
    __shared__ __align__(16) unsigned char hbuf[256];   // int8 h (200 used)
    __shared__ float a_lds[800];                        // gate activations [q*200+ko]
    int tid = threadIdx.x;
    int lane = tid & 63;
    int dir = blockIdx.x >> 6;
    int b = blockIdx.x & 63;
    bool act = tid < 800;
    int tw = act ? tid : 0;
    int q = tid / 200;

    const unsigned char* wbase = (const unsigned char*)w8 + dir * 160000;
    // stage chunks 0..7 (first 102,400 B of this dir, layout-identical) into LDS
    {
        const uint4* src = (const uint4*)wbase;
        for (int i = tid; i < 6400; i += 832) wlds[i] = src[i];
    }
    // register part: chunks 8..11 + tail = 72 B = 18 VGPRs
    uint4 wr[4];
    uint2 wt;
#pragma unroll
    for (int jj = 0; jj < 4; ++jj)
        wr[jj] = *(const uint4*)(wbase + (size_t)((8 + jj) * 800 + tw) * 16);
    wt = *(const uint2*)(wbase + 153600 + (size_t)tw * 8);
#pragma unroll
    for (int jj = 0; jj < 4; ++jj)
        asm volatile("" : "+v"(wr[jj].x), "+v"(wr[jj].y), "+v"(wr[jj].z), "+v"(wr[jj].w));
    asm volatile("" : "+v"(wt.x), "+v"(wt.y));

    float invsc = act ? invs[dir * 800 + tid] : 0.f;
    if (tid < 64) ((unsigned*)hbuf)[tid] = 0u;   // h=0 (full 256B)
    float c = 0.f;
    __syncthreads();

    const unsigned short* xbase = xg + (long)b * L_ * NG_ + dir * 800;
    int t0 = dir ? (L_ - 1) : 0;
    float x = act ? bf16_to_f32(xbase[(long)t0 * NG_ + tid]) : 0.f;

    for (int step = 0; step < L_; ++step) {
        int t = dir ? (L_ - 1 - step) : step;
        float x_n = 0.f;
        if (act && step + 1 < L_) {
            int tn = dir ? (t - 1) : (t + 1);
            x_n = bf16_to_f32(xbase[(long)tn * NG_ + tid]);
        }
        // one b128/wave: lane j holds h chunk j (13 lanes used; others read chunk 0, harmless)
        uint4 hv = ((const uint4*)hbuf)[lane < 13 ? lane : 0];
        if (act) {
            int di = 0;
#pragma unroll
            for (int j = 0; j < 8; ++j) {           // LDS chunks
                uint4 wv = wlds[j * 800 + tw];
                di = dot4(wv.x, rlane(hv.x, j), di);
                di = dot4(wv.y, rlane(hv.y, j), di);
                di = dot4(wv.z, rlane(hv.z, j), di);
                di = dot4(wv.w, rlane(hv.w, j), di);
            }
#pragma unroll
            for (int jj = 0; jj < 4; ++jj) {        // register chunks (j=8..11)
                di = dot4(wr[jj].x, rlane(hv.x, 8 + jj), di);
                di = dot4(wr[jj].y, rlane(hv.y, 8 + jj), di);
                di = dot4(wr[jj].z, rlane(hv.z, 8 + jj), di);
                di = dot4(wr[jj].w, rlane(hv.w, 8 + jj), di);
            }
            di = dot4(wt.x, rlane(hv.x, 12), di);   // tail k=192..199
            di = dot4(wt.y, rlane(hv.y, 12), di);
            float p = x + (float)di * invsc;
            float av;
            if (q == 2) {
                float e = __expf(-2.f * p);          // tanh
                av = 2.f / (1.f + e) - 1.f;
            } else {
                av = 1.f / (1.f + __expf(-p));       // sigmoid
            }
            a_lds[tid] = av;
        }
        __syncthreads();
        if (tid < HD_) {
            float ig = a_lds[tid];
            float fg = a_lds[200 + tid];
            float gg = a_lds[400 + tid];
            float og = a_lds[600 + tid];
            c = fg * c + ig * gg;
            float ec = __expf(-2.f * c);
            float hn = og * (2.f / (1.f + ec) - 1.f);
            ((signed char*)hbuf)[tid] = (signed char)(int)rintf(hn * 127.f);
            lstm_out[((long)(b * L_ + t)) * H_ + dir * HD_ + tid] = hn;
        }
        x = x_n;
        __syncthreads();
    }
}

// ---------------- features = lstm_out @ W_tag^T + b_tag (unchanged)
__global__ __launch_bounds__(256) void feat_kernel(const float* __restrict__ lstm_out,
                                                   const float* __restrict__ wtagT,
                                                   const float* __restrict__ btag,
                                                   float* __restrict__ feats) {
    __shared__ float hrow[4 * H_];
    int tid = threadIdx.x;
    int base = blockIdx.x * 4;
    for (int idx = tid; idx < 4 * H_; idx += 256)
        hrow[idx] = lstm_out[(long)base * H_ + idx];
    __syncthreads();
    int il = tid >> 6, s = tid & 63;
    if (s < S_) {
        float acc = btag[s];
        const float* hr = hrow + il * H_;
#pragma unroll 4
        for (int k = 0; k < H_; ++k)
            acc = fmaf(hr[k], wtagT[k * S_ + s], acc);
        feats[(base + il) * S_ + s] = acc;
    }
}

// ---------------- CRF forward + labeled score (per-batch partials, no atomics)
__global__ __launch_bounds__(512) void crf_kernel(const float* __restrict__ feats,
                                                  const float* __restrict__ trans,
                                                  const int* __restrict__ tags,
                                                  const int* __restrict__ seqlens,
                                                  float* __restrict__ part) {
    __shared__ float Tt[S_ * S_];   // Tt[j*50+i] = trans[i*50+j]
    __shared__ float alpha[S_];
    __shared__ float lastal[S_];
    __shared__ int tg[L_];
    int tid = threadIdx.x;
    int b = blockIdx.x;
    for (int idx = tid; idx < S_ * S_; idx += 512) {
        int j = idx / S_, i = idx % S_;
        Tt[idx] = trans[i * S_ + j];
    }
    if (tid < L_) tg[tid] = tags[b * L_ + tid];
    int slen = seqlens[b];
    const float* fb = feats + (long)b * L_ * S_;
    __syncthreads();
    if (tid < S_) {
        float a = Tt[tid * S_ + START_] + fb[tid];
        alpha[tid] = a;
        if (slen == 1) lastal[tid] = a;
    }
    __syncthreads();
    int j = tid >> 3, sub = tid & 7;
    bool jact = j < S_;
    for (int t = 1; t < L_; ++t) {
        float anew = 0.f;
        if (jact) {
            float m = -1e30f;
            for (int i = sub; i < S_; i += 8) m = fmaxf(m, alpha[i] + Tt[j * S_ + i]);
            m = fmaxf(m, __shfl_xor(m, 1));
            m = fmaxf(m, __shfl_xor(m, 2));
            m = fmaxf(m, __shfl_xor(m, 4));
            float s = 0.f;
            for (int i = sub; i < S_; i += 8) s += __expf(alpha[i] + Tt[j * S_ + i] - m);
            s += __shfl_xor(s, 1);
            s += __shfl_xor(s, 2);
            s += __shfl_xor(s, 4);
            anew = m + __logf(s) + fb[t * S_ + j];
        }
        __syncthreads();
        if (jact && sub == 0) {
            alpha[j] = anew;
            if (t == slen - 1) lastal[j] = anew;
        }
        __syncthreads();
    }
    if (tid < 64) {
        float la = (tid < S_) ? (lastal[tid] + Tt[END_ * S_ + tid]) : -1e30f;
        float m = la;
        for (int off = 32; off; off >>= 1) m = fmaxf(m, __shfl_xor(m, off));
        float e = (tid < S_) ? __expf(la - m) : 0.f;
        for (int off = 32; off; off >>= 1) e += __shfl_xor(e, off);
        float unl = m + __logf(e);
        float lab = 0.f;
        for (int tt = tid; tt < L_; tt += 64) {
            if (tt == 0) {
                lab += Tt[tg[0] * S_ + START_] + fb[tg[0]];
            } else if (tt < slen) {
                lab += Tt[tg[tt] * S_ + tg[tt - 1]] + fb[tt * S_ + tg[tt]];
            }
        }
        if (tid == 0) lab += Tt[END_ * S_ + tg[slen - 1]];
        for (int off = 32; off; off >>= 1) lab += __shfl_xor(lab, off);
        if (tid == 0) part[b] = unl - lab;
    }
}

// ---------------- final: deterministic fixed-order sum of 64 partials
__global__ void fin_kernel(const float* __restrict__ part, float* __restrict__ out) {
    float s = 0.f;
    for (int i = 0; i < B_; ++i) s += part[i];
    out[0] = s;
}

extern "C" void kernel_launch(void* const* d_in, const int* in_sizes, int n_in,
                              void* d_out, int out_size, void* d_ws, size_t ws_size,
                              hipStream_t stream) {
    const int*   words = (const int*)d_in[0];
    const int*   slens = (const int*)d_in[1];
    // d_in[2] = masks: semantically (t < seq_len); not read.
    const int*   tags  = (const int*)d_in[3];
    const float* emb   = (const float*)d_in[4];
    const float* wihf  = (const float*)d_in[5];
    const float* whhf  = (const float*)d_in[6];
    const float* bf    = (const float*)d_in[7];
    const float* wihb  = (const float*)d_in[8];
    const float* whhb  = (const float*)d_in[9];
    const float* bb    = (const float*)d_in[10];
    const float* wtag  = (const float*)d_in[11];
    const float* btag  = (const float*)d_in[12];
    const float* trans = (const float*)d_in[13];

    char* ws = (char*)d_ws;
    unsigned short* xg   = (unsigned short*)(ws + OFF_XG);
    float*          lstm = (float*)(ws + OFF_LSTM);
    unsigned short* Abf  = (unsigned short*)(ws + OFF_ABF);  // prep -> xg (overlays lstm)
    unsigned short* Bbf  = (unsigned short*)(ws + OFF_BBF);  // prep -> xg (overlays lstm)
    signed char*    w8   = (signed char*)(ws + OFF_SH);      // quant -> lstm
    float*          fts  = (float*)(ws + OFF_SH);            // feat -> crf (time-shared)
    float*          invs = (float*)(ws + OFF_INV);
    float*          wtT  = (float*)(ws + OFF_WTT);
    float*          biaC = (float*)(ws + OFF_BIA);
    float*          part = (float*)(ws + OFF_PART);
    float*          out  = (float*)d_out;

    prep_kernel<<<PREP_BLOCKS, 256, 0, stream>>>(words, emb, wihf, wihb, bf, bb,
                                                 wtag, Abf, Bbf, wtT, biaC);
    quant_kernel<<<400, 256, 0, stream>>>(whhf, whhb, w8, invs);
    xg_gemm<<<dim3(13, 64), 256, 0, stream>>>(Abf, Bbf, biaC, xg);
    lstm_rec<<<128, 832, 0, stream>>>(xg, w8, invs, lstm);
    feat_kernel<<<2048, 256, 0, stream>>>(lstm, wtT, btag, fts);
    crf_kernel<<<64, 512, 0, stream>>>(fts, trans, tags, slens, part);
    fin_kernel<<<1, 1, 0, stream>>>(part, out);
}